// Round 1
// 370.350 us; speedup vs baseline: 1.2844x; 1.2844x over previous
//
#include <hip/hip_runtime.h>

#define Tn 200
#define Dn 64
#define Hn 64
#define CC 16   // chunk size for fallback kernel

typedef _Float16 half2v __attribute__((ext_vector_type(2)));
typedef _Float16 half8v __attribute__((ext_vector_type(8)));
typedef float    f32x4  __attribute__((ext_vector_type(4)));

__device__ __forceinline__ float fast_sigmoid(float v) {
    return __builtin_amdgcn_rcpf(1.0f + __expf(-v));
}
__device__ __forceinline__ float fast_tanh(float v) {
    return 1.0f - 2.0f * __builtin_amdgcn_rcpf(1.0f + __expf(2.0f * v));
}
// Intra-wave LDS ordering (wave64 lockstep): drain lgkm queue + compiler fence.
__device__ __forceinline__ void wave_lds_fence() {
    asm volatile("s_waitcnt lgkmcnt(0)" ::: "memory");
}

__device__ __forceinline__ half8v cvt8(const float4 a, const float4 b) {
    return half8v{(_Float16)a.x, (_Float16)a.y, (_Float16)a.z, (_Float16)a.w,
                  (_Float16)b.x, (_Float16)b.y, (_Float16)b.z, (_Float16)b.w};
}

// ============================================================================
// Kernel 1 (NEW): x-projection as an MFMA GEMM over flat rows.
//   P[row][n] = X[row][:64] . W[:64][n] + bias[n],  row=(b,t) flat, n in [0,192)
//   W[k][n] = n<128 ? gk[k*128+n] : ck[k*64+(n-128)]
// Block = 4 waves; wave w owns cols [w*48, w*48+48) = 3 N-tiles of 16.
// Weight fragments live in registers for the whole grid-stride loop.
// Per 16-row subtile: skip entirely if no row is valid (t < len[b]);
// stores masked per element. No LDS, no barriers.
// ============================================================================
__global__ __launch_bounds__(256, 4)
void augru_proj_mfma(const float* __restrict__ x,     // [B*T, 64]
                     const int*   __restrict__ slen,  // [B]
                     const float* __restrict__ gk,    // [128][128]
                     const float* __restrict__ gb,    // [128]
                     const float* __restrict__ ck,    // [128][64]
                     const float* __restrict__ cb,    // [64]
                     _Float16*    __restrict__ P,     // [B*T, 192] fp16
                     int nrows, int nchunks)
{
    const int tid  = threadIdx.x;
    const int w    = tid >> 6;      // wave id 0..3
    const int lane = tid & 63;
    const int lm   = lane & 15;     // M (A) / N (B,C) index inside fragment
    const int kq   = lane >> 4;     // K quadrant

    // ---- one-time weight fragment + bias load (registers, persistent) ----
    // B-frag layout (16x16x32): n = lane&15, k = (lane>>4)*8 + e
    half8v bf[3][2];
    float  bias[3];
#pragma unroll
    for (int nt = 0; nt < 3; ++nt) {
        const int n = w * 48 + nt * 16 + lm;
#pragma unroll
        for (int kh = 0; kh < 2; ++kh) {
            const int kb = kh * 32 + kq * 8;
            half8v f;
#pragma unroll
            for (int e = 0; e < 8; ++e) {
                const int k = kb + e;
                const float v = (n < 128) ? gk[k * 128 + n]
                                          : ck[k * 64 + (n - 128)];
                f[e] = (_Float16)v;
            }
            bf[nt][kh] = f;
        }
        bias[nt] = (n < 128) ? gb[n] : cb[n - 128];
    }

    for (int chunk = blockIdx.x; chunk < nchunks; chunk += gridDim.x) {
        const int rb0 = chunk * 64;
#pragma unroll
        for (int sub = 0; sub < 4; ++sub) {
            const int rb = rb0 + sub * 16;

            // --- subtile validity: lane lm checks row rb+lm ---
            const int rowv = rb + lm;
            const int bv   = rowv / Tn;
            const int tv   = rowv - bv * Tn;
            const bool v   = (rowv < nrows) && (tv < slen[bv]);
            if (__ballot(v) == 0ull) continue;   // whole subtile past seq len

            // --- A fragments straight from global (m = lane&15, k = kq*8+e) ---
            const int rowA = min(rb + lm, nrows - 1);
            const float* xr = x + (size_t)rowA * Dn + kq * 8;
            const float4 q0 = *(const float4*)(xr);
            const float4 q1 = *(const float4*)(xr + 4);
            const float4 q2 = *(const float4*)(xr + 32);
            const float4 q3 = *(const float4*)(xr + 36);
            const half8v a0 = cvt8(q0, q1);   // k = 0..31 slice
            const half8v a1 = cvt8(q2, q3);   // k = 32..63 slice

            // --- MFMA: 3 N-tiles x (K=64 as 2x K32), bias preloaded in C ---
            f32x4 acc[3];
#pragma unroll
            for (int nt = 0; nt < 3; ++nt) {
                f32x4 c = {bias[nt], bias[nt], bias[nt], bias[nt]};
                c = __builtin_amdgcn_mfma_f32_16x16x32_f16(a0, bf[nt][0], c, 0, 0, 0);
                c = __builtin_amdgcn_mfma_f32_16x16x32_f16(a1, bf[nt][1], c, 0, 0, 0);
                acc[nt] = c;
            }

            // --- store, masked per row (C: col = lane&15, row = kq*4 + reg) ---
#pragma unroll
            for (int r = 0; r < 4; ++r) {
                const int row = rb + kq * 4 + r;
                const int bb  = row / Tn;
                const int tt  = row - bb * Tn;
                if (row < nrows && tt < slen[bb]) {
                    _Float16* Pt = P + (size_t)row * 192 + w * 48 + lm;
                    Pt[0]  = (_Float16)acc[0][r];
                    Pt[16] = (_Float16)acc[1][r];
                    Pt[32] = (_Float16)acc[2][r];
                }
            }
        }
    }
}

// ============================================================================
// Kernel 2: recurrence only. 1 wave per row -> all 2048 rows resident at once,
// no barriers, P/att prefetched 1 step ahead in registers. (unchanged)
// ============================================================================
__global__ __launch_bounds__(64, 2)
void augru_rec(const _Float16* __restrict__ P,   // [B,T,3,64] fp16
               const int*     __restrict__ slen, // [B]
               const float*   __restrict__ att,  // [B,T]
               const float*   __restrict__ gk,   // [128][128]
               const float*   __restrict__ ck,   // [128][64]
               float*         __restrict__ out)  // [B,T,H]
{
    const int b = blockIdx.x;
    const int j = threadIdx.x;

    __shared__ __align__(16) _Float16 s_h[Hn];
    __shared__ __align__(16) _Float16 s_rh[Hn];

    half2v wr[32], wu[32], wc[32];   // h-part weight cols (K rows 64..127)
#pragma unroll
    for (int m = 0; m < 32; ++m) {
        const int k = 64 + 2 * m;
        wr[m] = half2v{(_Float16)gk[(k + 0) * 128 + j],
                       (_Float16)gk[(k + 1) * 128 + j]};
        wu[m] = half2v{(_Float16)gk[(k + 0) * 128 + 64 + j],
                       (_Float16)gk[(k + 1) * 128 + 64 + j]};
        wc[m] = half2v{(_Float16)ck[(k + 0) * 64 + j],
                       (_Float16)ck[(k + 1) * 64 + j]};
    }

    const int len = slen[b];
    const _Float16* Prow = P   + (size_t)b * Tn * 192;
    const float*    arow = att + (size_t)b * Tn;
    float*          orow = out + (size_t)b * Tn * Hn;

    float h = 0.0f;

    _Float16 pr_n = (_Float16)0, pu_n = (_Float16)0, pc_n = (_Float16)0;
    float a_n = 0.0f;
    if (len > 0) {
        pr_n = Prow[j]; pu_n = Prow[64 + j]; pc_n = Prow[128 + j];
        a_n  = arow[0];
    }

    for (int t = 0; t < len; ++t) {
        const float pr = (float)pr_n;    // loaded last iteration
        const float pu = (float)pu_n;
        const float pc = (float)pc_n;
        const float a  = a_n;
        const int tn = min(t + 1, len - 1);
        const _Float16* Pt = Prow + tn * 192;
        pr_n = Pt[j]; pu_n = Pt[64 + j]; pc_n = Pt[128 + j];
        a_n  = arow[tn];

        s_h[j] = (_Float16)h;
        wave_lds_fence();

        float r0 = pr, r1 = 0.f, u0 = pu, u1 = 0.f;
        const half8v* hv = (const half8v*)s_h;   // 8 x 16B broadcast reads
#pragma unroll
        for (int m8 = 0; m8 < 8; ++m8) {
            const half8v v = hv[m8];
            const half2v p0 = __builtin_shufflevector(v, v, 0, 1);
            const half2v p1 = __builtin_shufflevector(v, v, 2, 3);
            const half2v p2 = __builtin_shufflevector(v, v, 4, 5);
            const half2v p3 = __builtin_shufflevector(v, v, 6, 7);
            const int m = m8 * 4;
            r0 = __builtin_amdgcn_fdot2(p0, wr[m + 0], r0, false);
            r1 = __builtin_amdgcn_fdot2(p1, wr[m + 1], r1, false);
            r0 = __builtin_amdgcn_fdot2(p2, wr[m + 2], r0, false);
            r1 = __builtin_amdgcn_fdot2(p3, wr[m + 3], r1, false);
            u0 = __builtin_amdgcn_fdot2(p0, wu[m + 0], u0, false);
            u1 = __builtin_amdgcn_fdot2(p1, wu[m + 1], u1, false);
            u0 = __builtin_amdgcn_fdot2(p2, wu[m + 2], u0, false);
            u1 = __builtin_amdgcn_fdot2(p3, wu[m + 3], u1, false);
        }
        const float rg = fast_sigmoid(r0 + r1);
        const float ug = fast_sigmoid(u0 + u1);

        s_rh[j] = (_Float16)(rg * h);
        wave_lds_fence();

        float c0 = pc, c1 = 0.f;
        const half8v* rv = (const half8v*)s_rh;
#pragma unroll
        for (int m8 = 0; m8 < 8; ++m8) {
            const half8v v = rv[m8];
            const half2v p0 = __builtin_shufflevector(v, v, 0, 1);
            const half2v p1 = __builtin_shufflevector(v, v, 2, 3);
            const half2v p2 = __builtin_shufflevector(v, v, 4, 5);
            const half2v p3 = __builtin_shufflevector(v, v, 6, 7);
            const int m = m8 * 4;
            c0 = __builtin_amdgcn_fdot2(p0, wc[m + 0], c0, false);
            c1 = __builtin_amdgcn_fdot2(p1, wc[m + 1], c1, false);
            c0 = __builtin_amdgcn_fdot2(p2, wc[m + 2], c0, false);
            c1 = __builtin_amdgcn_fdot2(p3, wc[m + 3], c1, false);
        }
        const float cg = fast_tanh(c0 + c1);

        const float uh = (1.0f - a) * ug;
        h = uh * h + (1.0f - uh) * cg;
        orow[t * Hn + j] = h;
        wave_lds_fence();  // WAR before next t's s_h/s_rh writes
    }

    // ---- zero tail: out[b, len:T, :] = 0 ----
    float4 z;
    z.x = z.y = z.z = z.w = 0.0f;
    float* tail = orow + len * Hn;
    const int total = (Tn - len) * Hn;
    for (int i = j * 4; i < total; i += 64 * 4) {
        *(float4*)(tail + i) = z;
    }
}

// ============================================================================
// Fallback (R4 fused, 430 us) if ws is too small for P. (unchanged)
// ============================================================================
__global__ __launch_bounds__(128, 2)
void augru_fused_fb(const float* __restrict__ x, const int* __restrict__ slen,
                    const float* __restrict__ att, const float* __restrict__ gk,
                    const float* __restrict__ gb, const float* __restrict__ ck,
                    const float* __restrict__ cb, float* __restrict__ out)
{
    const int b    = blockIdx.x;
    const int tid  = threadIdx.x;
    const int wave = tid >> 6;
    const int j    = tid & 63;

    __shared__ float s_P[2][CC][3][Hn];
    __shared__ __align__(16) _Float16 s_h[Hn];
    __shared__ __align__(16) _Float16 s_rh[Hn];

    const int len     = slen[b];
    const int nchunks = (len + CC - 1) / CC;
    const float* xrow = x   + (size_t)b * Tn * Dn;
    const float* arow = att + (size_t)b * Tn;
    float*       orow = out + (size_t)b * Tn * Hn;

    if (wave == 0) {
        half2v wr[32], wu[32], wc[32];
#pragma unroll
        for (int m = 0; m < 32; ++m) {
            const int k = 2 * m;
            wr[m] = half2v{(_Float16)gk[(k + 0) * 128 + j], (_Float16)gk[(k + 1) * 128 + j]};
            wu[m] = half2v{(_Float16)gk[(k + 0) * 128 + 64 + j], (_Float16)gk[(k + 1) * 128 + 64 + j]};
            wc[m] = half2v{(_Float16)ck[(k + 0) * 64 + j], (_Float16)ck[(k + 1) * 64 + j]};
        }
        const float br = gb[j], bu = gb[64 + j], bc = cb[j];
        for (int c = 0; c < nchunks; ++c) {
            const int t0 = c * CC, tend = min(len, t0 + CC);
            for (int t = t0; t < tend; ++t) {
                const float4* xv = (const float4*)(xrow + t * Dn);
                float r0 = br, r1 = 0.f, u0 = bu, u1 = 0.f, c0 = bc, c1 = 0.f;
#pragma unroll
                for (int kk = 0; kk < 16; ++kk) {
                    const float4 q = xv[kk];
                    const half2v p0 = half2v{(_Float16)q.x, (_Float16)q.y};
                    const half2v p1 = half2v{(_Float16)q.z, (_Float16)q.w};
                    const int m = 2 * kk;
                    r0 = __builtin_amdgcn_fdot2(p0, wr[m], r0, false);
                    r1 = __builtin_amdgcn_fdot2(p1, wr[m + 1], r1, false);
                    u0 = __builtin_amdgcn_fdot2(p0, wu[m], u0, false);
                    u1 = __builtin_amdgcn_fdot2(p1, wu[m + 1], u1, false);
                    c0 = __builtin_amdgcn_fdot2(p0, wc[m], c0, false);
                    c1 = __builtin_amdgcn_fdot2(p1, wc[m + 1], c1, false);
                }
                const int lt = t - t0;
                s_P[c & 1][lt][0][j] = r0 + r1;
                s_P[c & 1][lt][1][j] = u0 + u1;
                s_P[c & 1][lt][2][j] = c0 + c1;
            }
            __syncthreads();
        }
    } else {
        half2v wr[32], wu[32], wc[32];
#pragma unroll
        for (int m = 0; m < 32; ++m) {
            const int k = 64 + 2 * m;
            wr[m] = half2v{(_Float16)gk[(k + 0) * 128 + j], (_Float16)gk[(k + 1) * 128 + j]};
            wu[m] = half2v{(_Float16)gk[(k + 0) * 128 + 64 + j], (_Float16)gk[(k + 1) * 128 + 64 + j]};
            wc[m] = half2v{(_Float16)ck[(k + 0) * 64 + j], (_Float16)ck[(k + 1) * 64 + j]};
        }
        float h = 0.0f;
        for (int c = 0; c < nchunks; ++c) {
            __syncthreads();
            const int t0 = c * CC, tend = min(len, t0 + CC);
            for (int t = t0; t < tend; ++t) {
                const int lt = t - t0;
                const float pr = s_P[c & 1][lt][0][j];
                const float pu = s_P[c & 1][lt][1][j];
                const float pc = s_P[c & 1][lt][2][j];
                const float a  = arow[t];
                s_h[j] = (_Float16)h;
                wave_lds_fence();
                float r0 = pr, r1 = 0.f, u0 = pu, u1 = 0.f;
                const half8v* hv = (const half8v*)s_h;
#pragma unroll
                for (int m8 = 0; m8 < 8; ++m8) {
                    const half8v v = hv[m8];
                    const half2v p0 = __builtin_shufflevector(v, v, 0, 1);
                    const half2v p1 = __builtin_shufflevector(v, v, 2, 3);
                    const half2v p2 = __builtin_shufflevector(v, v, 4, 5);
                    const half2v p3 = __builtin_shufflevector(v, v, 6, 7);
                    const int m = m8 * 4;
                    r0 = __builtin_amdgcn_fdot2(p0, wr[m + 0], r0, false);
                    r1 = __builtin_amdgcn_fdot2(p1, wr[m + 1], r1, false);
                    r0 = __builtin_amdgcn_fdot2(p2, wr[m + 2], r0, false);
                    r1 = __builtin_amdgcn_fdot2(p3, wr[m + 3], r1, false);
                    u0 = __builtin_amdgcn_fdot2(p0, wu[m + 0], u0, false);
                    u1 = __builtin_amdgcn_fdot2(p1, wu[m + 1], u1, false);
                    u0 = __builtin_amdgcn_fdot2(p2, wu[m + 2], u0, false);
                    u1 = __builtin_amdgcn_fdot2(p3, wu[m + 3], u1, false);
                }
                const float rg = fast_sigmoid(r0 + r1);
                const float ug = fast_sigmoid(u0 + u1);
                s_rh[j] = (_Float16)(rg * h);
                wave_lds_fence();
                float c0 = pc, c1 = 0.f;
                const half8v* rv = (const half8v*)s_rh;
#pragma unroll
                for (int m8 = 0; m8 < 8; ++m8) {
                    const half8v v = rv[m8];
                    const half2v p0 = __builtin_shufflevector(v, v, 0, 1);
                    const half2v p1 = __builtin_shufflevector(v, v, 2, 3);
                    const half2v p2 = __builtin_shufflevector(v, v, 4, 5);
                    const half2v p3 = __builtin_shufflevector(v, v, 6, 7);
                    const int m = m8 * 4;
                    c0 = __builtin_amdgcn_fdot2(p0, wc[m + 0], c0, false);
                    c1 = __builtin_amdgcn_fdot2(p1, wc[m + 1], c1, false);
                    c0 = __builtin_amdgcn_fdot2(p2, wc[m + 2], c0, false);
                    c1 = __builtin_amdgcn_fdot2(p3, wc[m + 3], c1, false);
                }
                const float cg = fast_tanh(c0 + c1);
                const float uh = (1.0f - a) * ug;
                h = uh * h + (1.0f - uh) * cg;
                orow[t * Hn + j] = h;
                wave_lds_fence();
            }
        }
    }
    float4 z; z.x = z.y = z.z = z.w = 0.0f;
    float* tail = orow + len * Hn;
    const int total = (Tn - len) * Hn;
    for (int i = tid * 4; i < total; i += 128 * 4) *(float4*)(tail + i) = z;
}

extern "C" void kernel_launch(void* const* d_in, const int* in_sizes, int n_in,
                              void* d_out, int out_size, void* d_ws, size_t ws_size,
                              hipStream_t stream) {
    const float* x    = (const float*)d_in[0];
    const int*   slen = (const int*)  d_in[1];
    const float* att  = (const float*)d_in[2];
    const float* gk   = (const float*)d_in[3];
    const float* gb   = (const float*)d_in[4];
    const float* ck   = (const float*)d_in[5];
    const float* cb   = (const float*)d_in[6];
    float* out = (float*)d_out;

    const int B = in_sizes[1];  // 2048
    const size_t needP = (size_t)B * Tn * 192 * sizeof(_Float16);  // 157 MB

    if (ws_size >= needP) {
        _Float16* P = (_Float16*)d_ws;
        const int nrows   = B * Tn;
        const int nchunks = (nrows + 63) / 64;
        const int grid    = nchunks < 1024 ? nchunks : 1024;
        augru_proj_mfma<<<grid, 256, 0, stream>>>(x, slen, gk, gb, ck, cb, P,
                                                  nrows, nchunks);
        augru_rec<<<B, 64, 0, stream>>>(P, slen, att, gk, ck, out);
    } else {
        augru_fused_fb<<<B, 128, 0, stream>>>(x, slen, att, gk, gb, ck, cb, out);
    }
}